// Round 6
// baseline (166.462 us; speedup 1.0000x reference)
//
#include <hip/hip_runtime.h>
#include <hip/hip_bf16.h>

#define SQ 2048
#define NH 32
#define DH 128
#define NK 256
#define SCALE 0.08838834764831845f
#define LOG2E 1.4426950408889634f

typedef __attribute__((ext_vector_type(8))) __bf16 bf16x8;
typedef __attribute__((ext_vector_type(4))) float floatx4;

// LDS (bytes): pbuf [16 heads][256 keys] u16 = 8192
//            | kvbuf 16384: K chunk [64 keys][256B] or V^T [128 d][128B]
//            | stats 2x 64 floats
// All buffers XOR-swizzled on 16B granules: byte ^= ((row ^ row>>3)&7)<<4.
#define OFF_KV   8192
#define OFF_RED  (OFF_KV + 16384)   // 24576
#define OFF_RED2 (OFF_RED + 256)    // 24832
#define SMEM_SZ  25088              // LDS fits 6/CU; VGPR cap (256,5) -> 5 blocks/CU

#define SCHED_PIN() __builtin_amdgcn_sched_barrier(0)

__device__ __forceinline__ int swz(int row) { return ((row ^ (row >> 3)) & 7) << 4; }

__device__ __forceinline__ unsigned pk_bf16(float a, float b) {
  union { __hip_bfloat162 h2; unsigned u; } c;
  c.h2 = __float22bfloat162_rn(make_float2(a, b));
  return c.u;
}

__device__ __forceinline__ float fast_exp2(float x) {
#if __has_builtin(__builtin_amdgcn_exp2f)
  return __builtin_amdgcn_exp2f(x);
#else
  return exp2f(x);
#endif
}

// rotate within rows of 16 lanes (VALU DPP reductions)
template <int CTRL>
__device__ __forceinline__ float dpp_rot(float x) {
  int i = __builtin_bit_cast(int, x);
  i = __builtin_amdgcn_mov_dpp(i, CTRL, 0xF, 0xF, true);
  return __builtin_bit_cast(float, i);
}
#define RED16_MAX(v) { v = fmaxf(v, dpp_rot<0x121>(v)); v = fmaxf(v, dpp_rot<0x122>(v)); \
                       v = fmaxf(v, dpp_rot<0x124>(v)); v = fmaxf(v, dpp_rot<0x128>(v)); }
#define RED16_SUM(v) { v += dpp_rot<0x121>(v); v += dpp_rot<0x122>(v); \
                       v += dpp_rot<0x124>(v); v += dpp_rot<0x128>(v); }

// ---- pre-pass: kv fp32 [4096][2][128] -> bf16 in d_ws ----
__global__ __launch_bounds__(256) void kv_to_bf16(const float* __restrict__ kv,
                                                  unsigned short* __restrict__ kvb) {
  int i = blockIdx.x * 256 + threadIdx.x;
  float4 f = ((const float4*)kv)[i];
  uint2 o = { pk_bf16(f.x, f.y), pk_bf16(f.z, f.w) };
  ((uint2*)kvb)[i] = o;
}

struct KR { uint4 v[4]; };
struct VR { uint4 a, b, c, d; };

// K chunk gather: thread (r=tid>>2, seg=tid&3) covers 64B of gathered K row r.
__device__ __forceinline__ KR k_load(const unsigned short* __restrict__ kvb,
                                     const int* __restrict__ tkg, int c, int tid) {
  int r = tid >> 2, seg = tid & 3;
  int idx = tkg[c * 64 + r];
  const uint4* p = (const uint4*)(kvb + (size_t)idx * 256 + seg * 32);
  KR k;
#pragma unroll
  for (int i = 0; i < 4; i++) k.v[i] = p[i];
  return k;
}

__device__ __forceinline__ void k_write(char* kbuf, const KR& k, int tid) {
  int r = tid >> 2, seg = tid & 3;
  int base = r * 256 + seg * 64;
  int sw = swz(r);
#pragma unroll
  for (int i = 0; i < 4; i++)
    *(uint4*)(kbuf + ((base + i * 16) ^ sw)) = k.v[i];
}

__device__ __forceinline__ VR v_load(const unsigned short* __restrict__ kvb,
                                     const int* __restrict__ tkg, int c, int tid) {
  int rg = tid & 15, dg = tid >> 4;
  int r0 = rg * 4, d0 = dg * 8;
  int4 i4 = *(const int4*)&tkg[c * 64 + r0];
  VR v;
  v.a = *(const uint4*)(kvb + (size_t)i4.x * 256 + 128 + d0);
  v.b = *(const uint4*)(kvb + (size_t)i4.y * 256 + 128 + d0);
  v.c = *(const uint4*)(kvb + (size_t)i4.z * 256 + 128 + d0);
  v.d = *(const uint4*)(kvb + (size_t)i4.w * 256 + 128 + d0);
  return v;
}

// V^T store: rows d (128B each, swizzled), cols = key r0..r0+3 (uint2 = 4 bf16)
__device__ __forceinline__ void v_write(char* vbuf, const VR& v, int tid) {
  int rg = tid & 15, dg = tid >> 4;
  int r0 = rg * 4, d0 = dg * 8;
  const unsigned* pa = (const unsigned*)&v.a;
  const unsigned* pb = (const unsigned*)&v.b;
  const unsigned* pc = (const unsigned*)&v.c;
  const unsigned* pd = (const unsigned*)&v.d;
#pragma unroll
  for (int w = 0; w < 4; w++) {
    unsigned lo01 = __builtin_amdgcn_perm(pb[w], pa[w], 0x05040100u);
    unsigned lo23 = __builtin_amdgcn_perm(pd[w], pc[w], 0x05040100u);
    unsigned hi01 = __builtin_amdgcn_perm(pb[w], pa[w], 0x07060302u);
    unsigned hi23 = __builtin_amdgcn_perm(pd[w], pc[w], 0x07060302u);
    uint2 lo = { lo01, lo23 }, hi = { hi01, hi23 };
    int ra = d0 + 2 * w, rb = ra + 1;
    *(uint2*)(vbuf + ((ra * 128 + r0 * 2) ^ swz(ra))) = lo;
    *(uint2*)(vbuf + ((rb * 128 + r0 * 2) ^ swz(rb))) = hi;
  }
}

// GEMM1: 16 heads x 16 keys per wave per chunk (4 MFMA)
__device__ __forceinline__ void gemm1(const char* kbuf, const bf16x8 af[4],
                                      int nrow, int quad, floatx4& acc) {
  acc = (floatx4){0.f, 0.f, 0.f, 0.f};
  int sw = swz(nrow);
  __builtin_amdgcn_s_setprio(1);
#pragma unroll
  for (int ks = 0; ks < 4; ks++) {
    bf16x8 b = *(const bf16x8*)(kbuf + ((nrow * 256 + ks * 64 + quad * 16) ^ sw));
    acc = __builtin_amdgcn_mfma_f32_16x16x32_bf16(af[ks], b, acc, 0, 0, 0);
  }
  __builtin_amdgcn_s_setprio(0);
}

// PV: 16 heads x 32 d per wave per chunk (4 MFMA)
__device__ __forceinline__ void pv_chunk(const char* pbuf, const char* vbuf, int c,
                                         int wave, int quad, int l16,
                                         floatx4 oacc[2]) {
  __builtin_amdgcn_s_setprio(1);
#pragma unroll
  for (int ks = 0; ks < 2; ks++) {
    int kof = (c * 64 + ks * 32 + quad * 8) * 2;     // bytes within P row
    bf16x8 a = *(const bf16x8*)(pbuf + ((l16 * 512 + kof) ^ swz(l16)));
    int kl = (ks * 32 + quad * 8) * 2;               // bytes within V^T row
    int r0 = wave * 32 + l16, r1 = r0 + 16;
    bf16x8 b0 = *(const bf16x8*)(vbuf + ((r0 * 128 + kl) ^ swz(r0)));
    bf16x8 b1 = *(const bf16x8*)(vbuf + ((r1 * 128 + kl) ^ swz(r1)));
    oacc[0] = __builtin_amdgcn_mfma_f32_16x16x32_bf16(a, b0, oacc[0], 0, 0, 0);
    oacc[1] = __builtin_amdgcn_mfma_f32_16x16x32_bf16(a, b1, oacc[1], 0, 0, 0);
  }
  __builtin_amdgcn_s_setprio(0);
}

__global__ __launch_bounds__(256, 5) void sparse_attn_kernel(
    const float* __restrict__ q, const unsigned short* __restrict__ kvb,
    const float* __restrict__ sink, const int* __restrict__ topk,
    float* __restrict__ out) {
  __shared__ __align__(16) char smem[SMEM_SZ];
  char* pbuf  = smem;                 // P [16][256] u16, swizzled
  char* kvbuf = smem + OFF_KV;        // K chunk / V^T chunk, swizzled
  float* red  = (float*)(smem + OFF_RED);   // m_w[wave*16 + h]
  float* red2 = (float*)(smem + OFF_RED2);  // p_w[wave*16 + h]

  const int tid = threadIdx.x;
  const int s = blockIdx.x >> 1;
  const int h0 = (blockIdx.x & 1) * 16;   // this block's head group
  const int wave = tid >> 6;
  const int lane = tid & 63;
  const int quad = lane >> 4;
  const int l16 = lane & 15;
  const int* tkg = topk + (size_t)s * NK;

  // ---- Phase 0: K0 -> kvbuf (thru regs), K1 prefetch; Q direct-global ----
  {
    int r = tid >> 2, seg = tid & 3;
    int idx = tkg[r];
    const uint4* p = (const uint4*)(kvb + (size_t)idx * 256 + seg * 32);
    uint4 t0 = p[0], t1 = p[1], t2 = p[2], t3 = p[3];
    int base = r * 256 + seg * 64, sw = swz(r);
    *(uint4*)(kvbuf + ((base) ^ sw)) = t0;
    *(uint4*)(kvbuf + ((base + 16) ^ sw)) = t1;
    *(uint4*)(kvbuf + ((base + 32) ^ sw)) = t2;
    *(uint4*)(kvbuf + ((base + 48) ^ sw)) = t3;
  }
  KR k1 = k_load(kvb, tkg, 1, tid);
  SCHED_PIN();

  float snk[4];
#pragma unroll
  for (int r = 0; r < 4; r++)
    snk[r] = sink[h0 + quad * 4 + r] * LOG2E;

  // Q A-frags: lane owns head row h0+l16, k-segment quad*8 + ks*32 (pre-scaled)
  const float QSC = SCALE * LOG2E;
  const float* qrow = q + (size_t)s * (NH * DH) + (h0 + l16) * DH;
  bf16x8 afrag[4];
#pragma unroll
  for (int ks = 0; ks < 4; ks++) {
    const float* base = qrow + ks * 32 + quad * 8;
    float4 f0 = ((const float4*)base)[0];
    float4 f1 = ((const float4*)base)[1];
    uint4 u = { pk_bf16(f0.x * QSC, f0.y * QSC), pk_bf16(f0.z * QSC, f0.w * QSC),
                pk_bf16(f1.x * QSC, f1.y * QSC), pk_bf16(f1.z * QSC, f1.w * QSC) };
    afrag[ks] = __builtin_bit_cast(bf16x8, u);
  }
  __syncthreads();  // K0 visible

  const int nrow = wave * 16 + l16;

  // ---- Phase 1: GEMM1, single buffer, register prefetch pipeline ----
  floatx4 sc[4];
  KR k2 = k_load(kvb, tkg, 2, tid);
  SCHED_PIN();
  gemm1(kvbuf, afrag, nrow, quad, sc[0]);
  __syncthreads();              // c0 reads done
  k_write(kvbuf, k1, tid);
  __syncthreads();              // K1 visible
  KR k3 = k_load(kvb, tkg, 3, tid);
  SCHED_PIN();
  gemm1(kvbuf, afrag, nrow, quad, sc[1]);
  __syncthreads();
  k_write(kvbuf, k2, tid);
  __syncthreads();
  VR v0 = v_load(kvb, tkg, 0, tid);
  SCHED_PIN();
  gemm1(kvbuf, afrag, nrow, quad, sc[2]);
  __syncthreads();
  k_write(kvbuf, k3, tid);
  __syncthreads();
  VR v1 = v_load(kvb, tkg, 1, tid);
  SCHED_PIN();
  gemm1(kvbuf, afrag, nrow, quad, sc[3]);

  // ---- Phase 2: softmax (exp2 domain), flash-style single stats exchange ----
  float mh[4], ps[4];
#pragma unroll
  for (int r = 0; r < 4; r++) {
    float v = fmaxf(fmaxf(sc[0][r], sc[1][r]), fmaxf(sc[2][r], sc[3][r]));
    RED16_MAX(v);
    mh[r] = v;
  }
#pragma unroll
  for (int r = 0; r < 4; r++) {
    float acc = 0.f;
#pragma unroll
    for (int c = 0; c < 4; c++) {
      float e = fast_exp2(sc[c][r] - mh[r]);
      sc[c][r] = e;
      acc += e;
    }
    RED16_SUM(acc);
    ps[r] = acc;
  }
  if (l16 == 0) {
#pragma unroll
    for (int r = 0; r < 4; r++) {
      red[wave * 16 + quad * 4 + r]  = mh[r];
      red2[wave * 16 + quad * 4 + r] = ps[r];
    }
  }
  __syncthreads();  // stats visible + c3 reads done; K region dead
  v_write(kvbuf, v0, tid);            // V0 -> V^T (disjoint from stats)
  VR v2 = v_load(kvb, tkg, 2, tid);
  SCHED_PIN();
  float inv[4], sf[4];
#pragma unroll
  for (int r = 0; r < 4; r++) {
    int h = quad * 4 + r;
    float M = snk[r];
#pragma unroll
    for (int w = 0; w < 4; w++) M = fmaxf(M, red[w * 16 + h]);
    float dd = fast_exp2(snk[r] - M);
#pragma unroll
    for (int w = 0; w < 4; w++)
      dd += red2[w * 16 + h] * fast_exp2(red[w * 16 + h] - M);
    inv[r] = 1.0f / dd;
    sf[r] = fast_exp2(mh[r] - M);     // local->global rescale
  }
  // write P = e_local * sf (bf16, unnormalized) to pbuf, swizzled rows
#pragma unroll
  for (int c = 0; c < 4; c++) {
    int col = c * 64 + wave * 16 + l16;
    unsigned p01 = pk_bf16(sc[c][0] * sf[0], sc[c][1] * sf[1]);
    unsigned p23 = pk_bf16(sc[c][2] * sf[2], sc[c][3] * sf[3]);
    unsigned short vals[4] = { (unsigned short)p01, (unsigned short)(p01 >> 16),
                               (unsigned short)p23, (unsigned short)(p23 >> 16) };
#pragma unroll
    for (int j = 0; j < 4; j++) {
      int h = quad * 4 + j;
      *(unsigned short*)(pbuf + ((h * 512 + col * 2) ^ swz(h))) = vals[j];
    }
  }
  __syncthreads();  // pbuf + V0 visible

  // ---- Phase 3: O = P V, single buffer, register prefetch ----
  floatx4 oacc[2];
  oacc[0] = (floatx4){0.f, 0.f, 0.f, 0.f};
  oacc[1] = (floatx4){0.f, 0.f, 0.f, 0.f};

  VR v3 = v_load(kvb, tkg, 3, tid);
  SCHED_PIN();
  pv_chunk(pbuf, kvbuf, 0, wave, quad, l16, oacc);
  __syncthreads();              // pv0 reads done
  v_write(kvbuf, v1, tid);
  __syncthreads();              // V1 visible
  pv_chunk(pbuf, kvbuf, 1, wave, quad, l16, oacc);
  __syncthreads();
  v_write(kvbuf, v2, tid);
  __syncthreads();
  pv_chunk(pbuf, kvbuf, 2, wave, quad, l16, oacc);
  __syncthreads();
  v_write(kvbuf, v3, tid);
  __syncthreads();
  pv_chunk(pbuf, kvbuf, 3, wave, quad, l16, oacc);

  // ---- Phase 4: epilogue ----
  {
    float* op = out + (size_t)s * (NH * DH) + h0 * DH;
#pragma unroll
    for (int nt = 0; nt < 2; nt++)
#pragma unroll
      for (int r4 = 0; r4 < 4; r4++) {
        int h = quad * 4 + r4;
        int d = wave * 32 + nt * 16 + l16;
        op[h * DH + d] = oacc[nt][r4] * inv[r4];
      }
  }
}

extern "C" void kernel_launch(void* const* d_in, const int* in_sizes, int n_in,
                              void* d_out, int out_size, void* d_ws, size_t ws_size,
                              hipStream_t stream) {
  (void)in_sizes; (void)n_in; (void)out_size; (void)ws_size;
  const float* q    = (const float*)d_in[0];
  const float* kv   = (const float*)d_in[1];
  const float* sink = (const float*)d_in[2];
  const int*   topk = (const int*)d_in[3];
  float* out = (float*)d_out;
  unsigned short* kvb = (unsigned short*)d_ws;  // 2 MB bf16 KV

  kv_to_bf16<<<dim3(1024), dim3(256), 0, stream>>>(kv, kvb);
  sparse_attn_kernel<<<dim3(SQ * 2), dim3(256), 0, stream>>>(q, kvb, sink, topk, out);
}

// Round 7
// 124.918 us; speedup vs baseline: 1.3326x; 1.3326x over previous
//
#include <hip/hip_runtime.h>
#include <hip/hip_bf16.h>

#define SQ 2048
#define NH 32
#define DH 128
#define NK 256
#define SCALE 0.08838834764831845f
#define LOG2E 1.4426950408889634f

typedef __attribute__((ext_vector_type(8))) __bf16 bf16x8;
typedef __attribute__((ext_vector_type(4))) float floatx4;

// LDS (bytes), all XOR-swizzled on 16B granules: byte ^= ((row ^ row>>3)&7)<<4
//   pbuf  [32 heads][512 B]              = 16384
//   kvbuf K [64][256B] or V^T [128][128B] = 16384
//   red/red2 4 waves x 32 heads           = 512 + 512
#define OFF_KV   16384
#define OFF_RED  32768
#define OFF_RED2 33280
#define SMEM_SZ  33792   // x4 = 135168 <= 163840 -> 4 blocks/CU

#define SCHED_PIN() __builtin_amdgcn_sched_barrier(0)

__device__ __forceinline__ int swz(int row) { return ((row ^ (row >> 3)) & 7) << 4; }

__device__ __forceinline__ unsigned pk_bf16(float a, float b) {
  union { __hip_bfloat162 h2; unsigned u; } c;
  c.h2 = __float22bfloat162_rn(make_float2(a, b));
  return c.u;
}

__device__ __forceinline__ float fast_exp2(float x) {
#if __has_builtin(__builtin_amdgcn_exp2f)
  return __builtin_amdgcn_exp2f(x);
#else
  return exp2f(x);
#endif
}

// rotate within rows of 16 lanes (VALU DPP reductions)
template <int CTRL>
__device__ __forceinline__ float dpp_rot(float x) {
  int i = __builtin_bit_cast(int, x);
  i = __builtin_amdgcn_mov_dpp(i, CTRL, 0xF, 0xF, true);
  return __builtin_bit_cast(float, i);
}
#define RED16_MAX(v) { v = fmaxf(v, dpp_rot<0x121>(v)); v = fmaxf(v, dpp_rot<0x122>(v)); \
                       v = fmaxf(v, dpp_rot<0x124>(v)); v = fmaxf(v, dpp_rot<0x128>(v)); }
#define RED16_SUM(v) { v += dpp_rot<0x121>(v); v += dpp_rot<0x122>(v); \
                       v += dpp_rot<0x124>(v); v += dpp_rot<0x128>(v); }

// ---- pre-pass: kv fp32 [4096][2][128] -> bf16 in d_ws ----
__global__ __launch_bounds__(256) void kv_to_bf16(const float* __restrict__ kv,
                                                  unsigned short* __restrict__ kvb) {
  int i = blockIdx.x * 256 + threadIdx.x;
  float4 f = ((const float4*)kv)[i];
  uint2 o = { pk_bf16(f.x, f.y), pk_bf16(f.z, f.w) };
  ((uint2*)kvb)[i] = o;
}

struct KR { uint4 v[4]; };
struct VR { uint4 a, b, c, d; };

// TRANSPOSED-COALESCED K gather: lane (r=tid>>2, c4=tid&3); instruction i reads
// row r's bytes i*64 + c4*16 — the row's 4 lanes cover ONE 64B line per
// instruction (16 line-transactions/instr instead of 64).
__device__ __forceinline__ KR k_load(const unsigned short* __restrict__ kvb,
                                     const int* __restrict__ tkg, int c, int tid) {
  int r = tid >> 2, c4 = tid & 3;
  int idx = tkg[c * 64 + r];
  const char* p = (const char*)(kvb + (size_t)idx * 256);
  KR k;
#pragma unroll
  for (int i = 0; i < 4; i++)
    k.v[i] = *(const uint4*)(p + i * 64 + c4 * 16);
  return k;
}

__device__ __forceinline__ void k_write(char* kbuf, const KR& k, int tid) {
  int r = tid >> 2, c4 = tid & 3;
  int sw = swz(r);
#pragma unroll
  for (int i = 0; i < 4; i++)
    *(uint4*)(kbuf + ((r * 256 + i * 64 + c4 * 16) ^ sw)) = k.v[i];
}

// V gather (already line-coalesced: 4 dg-lanes of a row share one 64B line)
__device__ __forceinline__ VR v_load(const unsigned short* __restrict__ kvb,
                                     const int* __restrict__ tkg, int c, int tid) {
  int rg = tid & 15, dg = tid >> 4;
  int r0 = rg * 4, d0 = dg * 8;
  int4 i4 = *(const int4*)&tkg[c * 64 + r0];
  VR v;
  v.a = *(const uint4*)(kvb + (size_t)i4.x * 256 + 128 + d0);
  v.b = *(const uint4*)(kvb + (size_t)i4.y * 256 + 128 + d0);
  v.c = *(const uint4*)(kvb + (size_t)i4.z * 256 + 128 + d0);
  v.d = *(const uint4*)(kvb + (size_t)i4.w * 256 + 128 + d0);
  return v;
}

// V^T store: rows d (128 B, swizzled), cols key r0..r0+3 (uint2 = 4 bf16)
__device__ __forceinline__ void v_write(char* vbuf, const VR& v, int tid) {
  int rg = tid & 15, dg = tid >> 4;
  int r0 = rg * 4, d0 = dg * 8;
  const unsigned* pa = (const unsigned*)&v.a;
  const unsigned* pb = (const unsigned*)&v.b;
  const unsigned* pc = (const unsigned*)&v.c;
  const unsigned* pd = (const unsigned*)&v.d;
#pragma unroll
  for (int w = 0; w < 4; w++) {
    unsigned lo01 = __builtin_amdgcn_perm(pb[w], pa[w], 0x05040100u);
    unsigned lo23 = __builtin_amdgcn_perm(pd[w], pc[w], 0x05040100u);
    unsigned hi01 = __builtin_amdgcn_perm(pb[w], pa[w], 0x07060302u);
    unsigned hi23 = __builtin_amdgcn_perm(pd[w], pc[w], 0x07060302u);
    uint2 lo = { lo01, lo23 }, hi = { hi01, hi23 };
    int ra = d0 + 2 * w, rb = ra + 1;
    *(uint2*)(vbuf + ((ra * 128 + r0 * 2) ^ swz(ra))) = lo;
    *(uint2*)(vbuf + ((rb * 128 + r0 * 2) ^ swz(rb))) = hi;
  }
}

// GEMM1: 32 heads x 16 keys per wave per chunk (8 MFMA)
__device__ __forceinline__ void gemm1(const char* kbuf, const bf16x8 af[2][4],
                                      int nrow, int quad, floatx4& a0, floatx4& a1) {
  a0 = (floatx4){0.f, 0.f, 0.f, 0.f};
  a1 = (floatx4){0.f, 0.f, 0.f, 0.f};
  int sw = swz(nrow);
  __builtin_amdgcn_s_setprio(1);
#pragma unroll
  for (int ks = 0; ks < 4; ks++) {
    bf16x8 b = *(const bf16x8*)(kbuf + ((nrow * 256 + ks * 64 + quad * 16) ^ sw));
    a0 = __builtin_amdgcn_mfma_f32_16x16x32_bf16(af[0][ks], b, a0, 0, 0, 0);
    a1 = __builtin_amdgcn_mfma_f32_16x16x32_bf16(af[1][ks], b, a1, 0, 0, 0);
  }
  __builtin_amdgcn_s_setprio(0);
}

// PV: 32 heads x 32 d per wave per chunk (8 MFMA)
__device__ __forceinline__ void pv_chunk(const char* pbuf, const char* vbuf, int c,
                                         int wave, int quad, int l16,
                                         floatx4 oacc[2][2]) {
  __builtin_amdgcn_s_setprio(1);
#pragma unroll
  for (int ks = 0; ks < 2; ks++) {
    int kof = (c * 64 + ks * 32 + quad * 8) * 2;
    bf16x8 a0 = *(const bf16x8*)(pbuf + ((l16 * 512 + kof) ^ swz(l16)));
    bf16x8 a1 = *(const bf16x8*)(pbuf + (((16 + l16) * 512 + kof) ^ swz(16 + l16)));
    int kl = (ks * 32 + quad * 8) * 2;
    int r0 = wave * 32 + l16, r1 = r0 + 16;
    bf16x8 b0 = *(const bf16x8*)(vbuf + ((r0 * 128 + kl) ^ swz(r0)));
    bf16x8 b1 = *(const bf16x8*)(vbuf + ((r1 * 128 + kl) ^ swz(r1)));
    oacc[0][0] = __builtin_amdgcn_mfma_f32_16x16x32_bf16(a0, b0, oacc[0][0], 0, 0, 0);
    oacc[0][1] = __builtin_amdgcn_mfma_f32_16x16x32_bf16(a0, b1, oacc[0][1], 0, 0, 0);
    oacc[1][0] = __builtin_amdgcn_mfma_f32_16x16x32_bf16(a1, b0, oacc[1][0], 0, 0, 0);
    oacc[1][1] = __builtin_amdgcn_mfma_f32_16x16x32_bf16(a1, b1, oacc[1][1], 0, 0, 0);
  }
  __builtin_amdgcn_s_setprio(0);
}

__global__ __launch_bounds__(256, 4) void sparse_attn_kernel(
    const float* __restrict__ q, const unsigned short* __restrict__ kvb,
    const float* __restrict__ sink, const int* __restrict__ topk,
    float* __restrict__ out) {
  __shared__ __align__(16) char smem[SMEM_SZ];
  char* pbuf  = smem;
  char* kvbuf = smem + OFF_KV;
  float* red  = (float*)(smem + OFF_RED);   // m_w[wave*32 + h]
  float* red2 = (float*)(smem + OFF_RED2);  // p_w[wave*32 + h]

  const int tid = threadIdx.x;
  const int s = blockIdx.x;
  const int wave = tid >> 6;
  const int lane = tid & 63;
  const int quad = lane >> 4;
  const int l16 = lane & 15;
  const int* tkg = topk + (size_t)s * NK;

  // ---- Phase 0: K0 -> LDS (transposed-coalesced), K1 prefetch, Q direct ----
  {
    int r = tid >> 2, c4 = tid & 3;
    int idx = tkg[r];
    const char* p = (const char*)(kvb + (size_t)idx * 256);
    uint4 t0 = *(const uint4*)(p + 0 * 64 + c4 * 16);
    uint4 t1 = *(const uint4*)(p + 1 * 64 + c4 * 16);
    uint4 t2 = *(const uint4*)(p + 2 * 64 + c4 * 16);
    uint4 t3 = *(const uint4*)(p + 3 * 64 + c4 * 16);
    int sw = swz(r);
    *(uint4*)(kvbuf + ((r * 256 + 0 * 64 + c4 * 16) ^ sw)) = t0;
    *(uint4*)(kvbuf + ((r * 256 + 1 * 64 + c4 * 16) ^ sw)) = t1;
    *(uint4*)(kvbuf + ((r * 256 + 2 * 64 + c4 * 16) ^ sw)) = t2;
    *(uint4*)(kvbuf + ((r * 256 + 3 * 64 + c4 * 16) ^ sw)) = t3;
  }
  KR k1 = k_load(kvb, tkg, 1, tid);
  SCHED_PIN();

  float snk[2][4];
#pragma unroll
  for (int mt = 0; mt < 2; mt++)
#pragma unroll
    for (int r = 0; r < 4; r++)
      snk[mt][r] = sink[mt * 16 + quad * 4 + r] * LOG2E;

  // Q A-frags direct from global, pre-scaled (staged per m-tile to cap pressure)
  const float QSC = SCALE * LOG2E;
  const float* qp = q + (size_t)s * (NH * DH);
  bf16x8 afrag[2][4];
#pragma unroll
  for (int mt = 0; mt < 2; mt++) {
    const float* qrow = qp + (mt * 16 + l16) * DH;
#pragma unroll
    for (int ks = 0; ks < 4; ks++) {
      const float* base = qrow + ks * 32 + quad * 8;
      float4 f0 = ((const float4*)base)[0];
      float4 f1 = ((const float4*)base)[1];
      uint4 u = { pk_bf16(f0.x * QSC, f0.y * QSC), pk_bf16(f0.z * QSC, f0.w * QSC),
                  pk_bf16(f1.x * QSC, f1.y * QSC), pk_bf16(f1.z * QSC, f1.w * QSC) };
      afrag[mt][ks] = __builtin_bit_cast(bf16x8, u);
    }
  }
  __syncthreads();  // K0 visible

  const int nrow = wave * 16 + l16;

  // ---- Phase 1: GEMM1, single buffer, 1-deep register prefetch ----
  floatx4 sc[4][2];
  gemm1(kvbuf, afrag, nrow, quad, sc[0][0], sc[0][1]);
  __syncthreads();              // c0 reads done
  k_write(kvbuf, k1, tid);
  KR k2 = k_load(kvb, tkg, 2, tid);
  SCHED_PIN();
  __syncthreads();              // K1 visible

  gemm1(kvbuf, afrag, nrow, quad, sc[1][0], sc[1][1]);
  __syncthreads();
  k_write(kvbuf, k2, tid);
  KR k3 = k_load(kvb, tkg, 3, tid);
  SCHED_PIN();
  __syncthreads();

  gemm1(kvbuf, afrag, nrow, quad, sc[2][0], sc[2][1]);
  __syncthreads();
  k_write(kvbuf, k3, tid);
  VR v0 = v_load(kvb, tkg, 0, tid);
  SCHED_PIN();
  __syncthreads();

  gemm1(kvbuf, afrag, nrow, quad, sc[3][0], sc[3][1]);

  // ---- Phase 2: softmax (exp2 domain), flash-style single stats exchange ----
  float mh[2][4], ps[2][4];
#pragma unroll
  for (int mt = 0; mt < 2; mt++)
#pragma unroll
    for (int r = 0; r < 4; r++) {
      float v = fmaxf(fmaxf(sc[0][mt][r], sc[1][mt][r]),
                      fmaxf(sc[2][mt][r], sc[3][mt][r]));
      RED16_MAX(v);
      mh[mt][r] = v;
    }
#pragma unroll
  for (int mt = 0; mt < 2; mt++)
#pragma unroll
    for (int r = 0; r < 4; r++) {
      float acc = 0.f;
#pragma unroll
      for (int c = 0; c < 4; c++) {
        float e = fast_exp2(sc[c][mt][r] - mh[mt][r]);
        sc[c][mt][r] = e;
        acc += e;
      }
      RED16_SUM(acc);
      ps[mt][r] = acc;
    }
  if (l16 == 0) {
#pragma unroll
    for (int mt = 0; mt < 2; mt++)
#pragma unroll
      for (int r = 0; r < 4; r++) {
        red[wave * 32 + mt * 16 + quad * 4 + r]  = mh[mt][r];
        red2[wave * 32 + mt * 16 + quad * 4 + r] = ps[mt][r];
      }
  }
  __syncthreads();  // stats visible AND all c3 kvbuf reads done
  v_write(kvbuf, v0, tid);            // V0 -> V^T
  VR v1 = v_load(kvb, tkg, 1, tid);
  SCHED_PIN();
  float inv[2][4], sf[2][4];
#pragma unroll
  for (int mt = 0; mt < 2; mt++)
#pragma unroll
    for (int r = 0; r < 4; r++) {
      int h = mt * 16 + quad * 4 + r;
      float M = snk[mt][r];
#pragma unroll
      for (int w = 0; w < 4; w++) M = fmaxf(M, red[w * 32 + h]);
      float dd = fast_exp2(snk[mt][r] - M);
#pragma unroll
      for (int w = 0; w < 4; w++)
        dd += red2[w * 32 + h] * fast_exp2(red[w * 32 + h] - M);
      inv[mt][r] = 1.0f / dd;
      sf[mt][r] = fast_exp2(mh[mt][r] - M);  // local->global rescale
    }
  // write P = e_local * sf (bf16, unnormalized) to pbuf [head][col], swizzled
#pragma unroll
  for (int c = 0; c < 4; c++)
#pragma unroll
    for (int mt = 0; mt < 2; mt++) {
      int col = c * 64 + wave * 16 + l16;
      unsigned p01 = pk_bf16(sc[c][mt][0] * sf[mt][0], sc[c][mt][1] * sf[mt][1]);
      unsigned p23 = pk_bf16(sc[c][mt][2] * sf[mt][2], sc[c][mt][3] * sf[mt][3]);
      unsigned short vals[4] = { (unsigned short)p01, (unsigned short)(p01 >> 16),
                                 (unsigned short)p23, (unsigned short)(p23 >> 16) };
#pragma unroll
      for (int j = 0; j < 4; j++) {
        int h = mt * 16 + quad * 4 + j;
        *(unsigned short*)(pbuf + ((h * 512 + col * 2) ^ swz(h))) = vals[j];
      }
    }
  __syncthreads();  // pbuf + V0 visible

  // ---- Phase 3: O = P V, single buffer, 1-deep register prefetch ----
  floatx4 oacc[2][2];
#pragma unroll
  for (int mt = 0; mt < 2; mt++)
#pragma unroll
    for (int nt = 0; nt < 2; nt++)
      oacc[mt][nt] = (floatx4){0.f, 0.f, 0.f, 0.f};

  pv_chunk(pbuf, kvbuf, 0, wave, quad, l16, oacc);
  __syncthreads();              // pv0 reads done
  v_write(kvbuf, v1, tid);
  VR v2 = v_load(kvb, tkg, 2, tid);
  SCHED_PIN();
  __syncthreads();              // V1 visible

  pv_chunk(pbuf, kvbuf, 1, wave, quad, l16, oacc);
  __syncthreads();
  v_write(kvbuf, v2, tid);
  VR v3 = v_load(kvb, tkg, 3, tid);
  SCHED_PIN();
  __syncthreads();

  pv_chunk(pbuf, kvbuf, 2, wave, quad, l16, oacc);
  __syncthreads();
  v_write(kvbuf, v3, tid);
  __syncthreads();

  pv_chunk(pbuf, kvbuf, 3, wave, quad, l16, oacc);

  // ---- Phase 4: epilogue ----
  {
    float* op = out + (size_t)s * (NH * DH);
#pragma unroll
    for (int mt = 0; mt < 2; mt++)
#pragma unroll
      for (int nt = 0; nt < 2; nt++)
#pragma unroll
        for (int r4 = 0; r4 < 4; r4++) {
          int h = mt * 16 + quad * 4 + r4;
          int d = wave * 32 + nt * 16 + l16;
          op[h * DH + d] = oacc[mt][nt][r4] * inv[mt][r4];
        }
  }
}

extern "C" void kernel_launch(void* const* d_in, const int* in_sizes, int n_in,
                              void* d_out, int out_size, void* d_ws, size_t ws_size,
                              hipStream_t stream) {
  (void)in_sizes; (void)n_in; (void)out_size; (void)ws_size;
  const float* q    = (const float*)d_in[0];
  const float* kv   = (const float*)d_in[1];
  const float* sink = (const float*)d_in[2];
  const int*   topk = (const int*)d_in[3];
  float* out = (float*)d_out;
  unsigned short* kvb = (unsigned short*)d_ws;  // 2 MB bf16 KV

  kv_to_bf16<<<dim3(1024), dim3(256), 0, stream>>>(kv, kvb);
  sparse_attn_kernel<<<dim3(SQ), dim3(256), 0, stream>>>(q, kvb, sink, topk, out);
}

// Round 8
// 115.024 us; speedup vs baseline: 1.4472x; 1.0860x over previous
//
#include <hip/hip_runtime.h>
#include <hip/hip_bf16.h>

#define SQ 2048
#define NH 32
#define DH 128
#define NK 256
#define SCALE 0.08838834764831845f
#define LOG2E 1.4426950408889634f

typedef __attribute__((ext_vector_type(8))) __bf16 bf16x8;
typedef __attribute__((ext_vector_type(4))) float floatx4;

// element strides (u16)
#define QS_STRIDE 136   // Q staged rows, 272 B (16B-aligned, 2-way banks = free)
#define KS_STRIDE 136   // K chunk [64][136]; 272 B rows
#define VB_STRIDE 72    // V transposed [d][k_local]; 144 B rows
#define PB_STRIDE 264   // P [head][col]; 528 B rows

// LDS (bytes): pbuf 16896 | dbuf0 18432 | dbuf1 18432 ; red/red2 in dbuf1 tail
#define OFF_DB0  16896
#define DBSZ     18432
#define OFF_DB1  (OFF_DB0 + DBSZ)          // 35328
#define OFF_RED  (OFF_DB1 + 17408)         // 52736: 128 floats (m_w)
#define OFF_RED2 (OFF_RED + 512)           // 53248: 128 floats (p_w)
#define SMEM_SZ  53760                     // x3 = 161280 <= 163840 -> 3 blocks/CU

#define SCHED_PIN() __builtin_amdgcn_sched_barrier(0)

__device__ __forceinline__ unsigned pk_bf16(float a, float b) {
  union { __hip_bfloat162 h2; unsigned u; } c;
  c.h2 = __float22bfloat162_rn(make_float2(a, b));
  return c.u;
}

__device__ __forceinline__ float fast_exp2(float x) {
#if __has_builtin(__builtin_amdgcn_exp2f)
  return __builtin_amdgcn_exp2f(x);
#else
  return exp2f(x);
#endif
}

template <int CTRL>
__device__ __forceinline__ float dpp_rot(float x) {
  int i = __builtin_bit_cast(int, x);
  i = __builtin_amdgcn_mov_dpp(i, CTRL, 0xF, 0xF, true);
  return __builtin_bit_cast(float, i);
}
#define RED16_MAX(v) { v = fmaxf(v, dpp_rot<0x121>(v)); v = fmaxf(v, dpp_rot<0x122>(v)); \
                       v = fmaxf(v, dpp_rot<0x124>(v)); v = fmaxf(v, dpp_rot<0x128>(v)); }
#define RED16_SUM(v) { v += dpp_rot<0x121>(v); v += dpp_rot<0x122>(v); \
                       v += dpp_rot<0x124>(v); v += dpp_rot<0x128>(v); }

// ---- pre-pass: kv fp32 [4096][2][128] -> bf16 in d_ws ----
__global__ __launch_bounds__(256) void kv_to_bf16(const float* __restrict__ kv,
                                                  unsigned short* __restrict__ kvb) {
  int i = blockIdx.x * 256 + threadIdx.x;
  float4 f = ((const float4*)kv)[i];
  uint2 o = { pk_bf16(f.x, f.y), pk_bf16(f.z, f.w) };
  ((uint2*)kvb)[i] = o;
}

struct KR { uint4 v[4]; };
struct VR { uint4 a, b, c, d; };

// TRANSPOSED-COALESCED K gather: lane (r=tid>>2, c4=tid&3); instruction i reads
// row r's bytes i*64 + c4*16 — the row's 4 lanes cover ONE 64B line per
// instruction (16 L1 line-lookups/instr instead of 64). Byte-set per row is
// identical to the old seg-layout, so LDS placement and gemm1 are unchanged.
__device__ __forceinline__ KR k_load(const unsigned short* __restrict__ kvb,
                                     const int* __restrict__ tkg, int c, int tid) {
  int r = tid >> 2, c4 = tid & 3;
  int idx = tkg[c * 64 + r];
  const char* p = (const char*)(kvb + (size_t)idx * 256);
  KR k;
#pragma unroll
  for (int i = 0; i < 4; i++)
    k.v[i] = *(const uint4*)(p + i * 64 + c4 * 16);
  return k;
}

__device__ __forceinline__ void k_write(unsigned short* kbuf, const KR& k, int tid) {
  int r = tid >> 2, c4 = tid & 3;
  char* rowp = (char*)&kbuf[r * KS_STRIDE];
#pragma unroll
  for (int i = 0; i < 4; i++)
    *(uint4*)(rowp + i * 64 + c4 * 16) = k.v[i];
}

// V gather: 4 dg-lanes of a row share one 64B line already (coalesced)
__device__ __forceinline__ VR v_load(const unsigned short* __restrict__ kvb,
                                     const int* __restrict__ tkg, int c, int tid) {
  int rg = tid & 15, dg = tid >> 4;
  int r0 = rg * 4, d0 = dg * 8;
  int4 i4 = *(const int4*)&tkg[c * 64 + r0];
  VR v;
  v.a = *(const uint4*)(kvb + (size_t)i4.x * 256 + 128 + d0);
  v.b = *(const uint4*)(kvb + (size_t)i4.y * 256 + 128 + d0);
  v.c = *(const uint4*)(kvb + (size_t)i4.z * 256 + 128 + d0);
  v.d = *(const uint4*)(kvb + (size_t)i4.w * 256 + 128 + d0);
  return v;
}

__device__ __forceinline__ void v_write(unsigned short* vbuf, const VR& v, int tid) {
  int rg = tid & 15, dg = tid >> 4;
  int r0 = rg * 4, d0 = dg * 8;
  const unsigned* pa = (const unsigned*)&v.a;
  const unsigned* pb = (const unsigned*)&v.b;
  const unsigned* pc = (const unsigned*)&v.c;
  const unsigned* pd = (const unsigned*)&v.d;
#pragma unroll
  for (int w = 0; w < 4; w++) {
    unsigned lo01 = __builtin_amdgcn_perm(pb[w], pa[w], 0x05040100u);
    unsigned lo23 = __builtin_amdgcn_perm(pd[w], pc[w], 0x05040100u);
    unsigned hi01 = __builtin_amdgcn_perm(pb[w], pa[w], 0x07060302u);
    unsigned hi23 = __builtin_amdgcn_perm(pd[w], pc[w], 0x07060302u);
    uint2 lo = { lo01, lo23 }, hi = { hi01, hi23 };
    *(uint2*)&vbuf[(d0 + 2 * w) * VB_STRIDE + r0] = lo;
    *(uint2*)&vbuf[(d0 + 2 * w + 1) * VB_STRIDE + r0] = hi;
  }
}

__device__ __forceinline__ void gemm1(const unsigned short* kbuf,
                                      const bf16x8 af[2][4], int nrow, int quad,
                                      floatx4& a0, floatx4& a1) {
  a0 = (floatx4){0.f, 0.f, 0.f, 0.f};
  a1 = (floatx4){0.f, 0.f, 0.f, 0.f};
  __builtin_amdgcn_s_setprio(1);
#pragma unroll
  for (int ks = 0; ks < 4; ks++) {
    bf16x8 b = *(const bf16x8*)&kbuf[nrow * KS_STRIDE + ks * 32 + quad * 8];
    a0 = __builtin_amdgcn_mfma_f32_16x16x32_bf16(af[0][ks], b, a0, 0, 0, 0);
    a1 = __builtin_amdgcn_mfma_f32_16x16x32_bf16(af[1][ks], b, a1, 0, 0, 0);
  }
  __builtin_amdgcn_s_setprio(0);
}

__device__ __forceinline__ void pv_chunk(const unsigned short* pbuf,
                                         const unsigned short* vbuf, int c,
                                         int wave, int quad, int l16,
                                         floatx4 oacc[2][2]) {
  __builtin_amdgcn_s_setprio(1);
#pragma unroll
  for (int ks = 0; ks < 2; ks++) {
    int kof = c * 64 + ks * 32 + quad * 8;
    bf16x8 a0 = *(const bf16x8*)&pbuf[l16 * PB_STRIDE + kof];
    bf16x8 a1 = *(const bf16x8*)&pbuf[(16 + l16) * PB_STRIDE + kof];
    int kl = ks * 32 + quad * 8;
    bf16x8 b0 = *(const bf16x8*)&vbuf[(wave * 32 + l16) * VB_STRIDE + kl];
    bf16x8 b1 = *(const bf16x8*)&vbuf[(wave * 32 + 16 + l16) * VB_STRIDE + kl];
    oacc[0][0] = __builtin_amdgcn_mfma_f32_16x16x32_bf16(a0, b0, oacc[0][0], 0, 0, 0);
    oacc[0][1] = __builtin_amdgcn_mfma_f32_16x16x32_bf16(a0, b1, oacc[0][1], 0, 0, 0);
    oacc[1][0] = __builtin_amdgcn_mfma_f32_16x16x32_bf16(a1, b0, oacc[1][0], 0, 0, 0);
    oacc[1][1] = __builtin_amdgcn_mfma_f32_16x16x32_bf16(a1, b1, oacc[1][1], 0, 0, 0);
  }
  __builtin_amdgcn_s_setprio(0);
}

__global__ __launch_bounds__(256, 3) void sparse_attn_kernel(
    const float* __restrict__ q, const unsigned short* __restrict__ kvb,
    const float* __restrict__ sink, const int* __restrict__ topk,
    float* __restrict__ out) {
  __shared__ __align__(16) char smem[SMEM_SZ];
  unsigned short* pbuf = (unsigned short*)smem;              // P [32][264]; qs overlay ph0
  unsigned short* qs   = (unsigned short*)smem;
  unsigned short* db0  = (unsigned short*)(smem + OFF_DB0);  // K/V^T double buffer
  unsigned short* db1  = (unsigned short*)(smem + OFF_DB1);
  float* red  = (float*)(smem + OFF_RED);    // per-wave local max  m_w[wave][head]
  float* red2 = (float*)(smem + OFF_RED2);   // per-wave local sum  p_w[wave][head]

  const int tid = threadIdx.x;
  const int s = blockIdx.x;
  const int wave = tid >> 6;
  const int lane = tid & 63;
  const int quad = lane >> 4;
  const int l16 = lane & 15;
  const int* tkg = topk + (size_t)s * NK;
  unsigned short* dbuf[2] = { db0, db1 };

  // ---- Phase 0: K0 -> db0 (transposed-coalesced), k1 prefetch, Q staged ----
  {
    int r = tid >> 2, c4 = tid & 3;
    int idx = tkg[r];
    const char* p = (const char*)(kvb + (size_t)idx * 256);
    uint4 t0 = *(const uint4*)(p + 0 * 64 + c4 * 16);
    uint4 t1 = *(const uint4*)(p + 1 * 64 + c4 * 16);
    uint4 t2 = *(const uint4*)(p + 2 * 64 + c4 * 16);
    uint4 t3 = *(const uint4*)(p + 3 * 64 + c4 * 16);
    char* rowp = (char*)&db0[r * KS_STRIDE];
    *(uint4*)(rowp + 0 * 64 + c4 * 16) = t0;
    *(uint4*)(rowp + 1 * 64 + c4 * 16) = t1;
    *(uint4*)(rowp + 2 * 64 + c4 * 16) = t2;
    *(uint4*)(rowp + 3 * 64 + c4 * 16) = t3;
  }
  KR k1 = k_load(kvb, tkg, 1, tid);
  SCHED_PIN();

  float snk[2][4];
#pragma unroll
  for (int mt = 0; mt < 2; mt++)
#pragma unroll
    for (int r = 0; r < 4; r++)
      snk[mt][r] = sink[mt * 16 + quad * 4 + r] * LOG2E;

  {  // Q stage, pre-scaled by SCALE*log2(e): softmax runs in exp2 domain
    const float QSC = SCALE * LOG2E;
    const float* qp = q + (size_t)s * (NH * DH);
    int h = tid >> 3, d0 = (tid & 7) * 16;
    const float4* src = (const float4*)(qp + h * DH + d0);
    float4 f0 = src[0], f1 = src[1], f2 = src[2], f3 = src[3];
    uint4 o0 = { pk_bf16(f0.x * QSC, f0.y * QSC), pk_bf16(f0.z * QSC, f0.w * QSC),
                 pk_bf16(f1.x * QSC, f1.y * QSC), pk_bf16(f1.z * QSC, f1.w * QSC) };
    uint4 o1 = { pk_bf16(f2.x * QSC, f2.y * QSC), pk_bf16(f2.z * QSC, f2.w * QSC),
                 pk_bf16(f3.x * QSC, f3.y * QSC), pk_bf16(f3.z * QSC, f3.w * QSC) };
    *(uint4*)&qs[h * QS_STRIDE + d0] = o0;
    *(uint4*)&qs[h * QS_STRIDE + d0 + 8] = o1;
  }
  __syncthreads();  // K0 + qs visible

  // Hoist Q A-fragments from LDS (qs dead afterwards; pbuf reuses the space)
  bf16x8 afrag[2][4];
#pragma unroll
  for (int mt = 0; mt < 2; mt++)
#pragma unroll
    for (int ks = 0; ks < 4; ks++)
      afrag[mt][ks] =
          *(const bf16x8*)&qs[(mt * 16 + l16) * QS_STRIDE + ks * 32 + quad * 8];

  const int nrow = wave * 16 + l16;

  // ---- Phase 1: GEMM1, double-buffered K: ONE barrier per chunk ----
  floatx4 sc[4][2];
  // c0: read db0 | write k1->db1 | issue k2
  KR k2 = k_load(kvb, tkg, 2, tid);
  SCHED_PIN();
  gemm1(dbuf[0], afrag, nrow, quad, sc[0][0], sc[0][1]);
  k_write(dbuf[1], k1, tid);
  __syncthreads();  // K1 visible; db0 reads done

  // c1: read db1 | write k2->db0 | issue k3
  KR k3 = k_load(kvb, tkg, 3, tid);
  SCHED_PIN();
  gemm1(dbuf[1], afrag, nrow, quad, sc[1][0], sc[1][1]);
  k_write(dbuf[0], k2, tid);
  __syncthreads();

  // c2: read db0 | write k3->db1 | issue v0
  VR v0 = v_load(kvb, tkg, 0, tid);
  SCHED_PIN();
  gemm1(dbuf[0], afrag, nrow, quad, sc[2][0], sc[2][1]);
  k_write(dbuf[1], k3, tid);
  __syncthreads();

  // c3: read db1 | write v0->db0 (V^T) | issue v1; NO barrier (stats barrier covers)
  VR v1 = v_load(kvb, tkg, 1, tid);
  SCHED_PIN();
  gemm1(dbuf[1], afrag, nrow, quad, sc[3][0], sc[3][1]);
  v_write(dbuf[0], v0, tid);

  // ---- Phase 2: softmax, flash-style single stats exchange ----
  float mh[2][4];
#pragma unroll
  for (int mt = 0; mt < 2; mt++)
#pragma unroll
    for (int r = 0; r < 4; r++) {
      float v = fmaxf(fmaxf(sc[0][mt][r], sc[1][mt][r]),
                      fmaxf(sc[2][mt][r], sc[3][mt][r]));
      RED16_MAX(v);
      mh[mt][r] = v;
    }
  float ps[2][4];
#pragma unroll
  for (int mt = 0; mt < 2; mt++)
#pragma unroll
    for (int r = 0; r < 4; r++) {
      float acc = 0.f;
#pragma unroll
      for (int c = 0; c < 4; c++) {
        float e = fast_exp2(sc[c][mt][r] - mh[mt][r]);
        sc[c][mt][r] = e;
        acc += e;
      }
      RED16_SUM(acc);
      ps[mt][r] = acc;
    }
  if (l16 == 0) {
#pragma unroll
    for (int mt = 0; mt < 2; mt++)
#pragma unroll
      for (int r = 0; r < 4; r++) {
        red[wave * 32 + mt * 16 + quad * 4 + r]  = mh[mt][r];
        red2[wave * 32 + mt * 16 + quad * 4 + r] = ps[mt][r];
      }
  }
  __syncthreads();  // stats visible (also covers c3's db1 reads)
  VR v2 = v_load(kvb, tkg, 2, tid);  // issue under the stats math
  SCHED_PIN();
  float inv[2][4], sf[2][4];
#pragma unroll
  for (int mt = 0; mt < 2; mt++)
#pragma unroll
    for (int r = 0; r < 4; r++) {
      int h = mt * 16 + quad * 4 + r;
      float M = snk[mt][r];
#pragma unroll
      for (int w = 0; w < 4; w++) M = fmaxf(M, red[w * 32 + h]);
      float dd = fast_exp2(snk[mt][r] - M);
#pragma unroll
      for (int w = 0; w < 4; w++)
        dd += red2[w * 32 + h] * fast_exp2(red[w * 32 + h] - M);
      inv[mt][r] = 1.0f / dd;
      sf[mt][r] = fast_exp2(mh[mt][r] - M);  // rescale local->global
    }
  // write P = e_local * sf (bf16, unnormalized) to pbuf [head][col]
#pragma unroll
  for (int c = 0; c < 4; c++)
#pragma unroll
    for (int mt = 0; mt < 2; mt++) {
      int col = c * 64 + wave * 16 + l16;
      unsigned short* pb = &pbuf[(mt * 16 + quad * 4) * PB_STRIDE + col];
      unsigned p01 = pk_bf16(sc[c][mt][0] * sf[mt][0], sc[c][mt][1] * sf[mt][1]);
      unsigned p23 = pk_bf16(sc[c][mt][2] * sf[mt][2], sc[c][mt][3] * sf[mt][3]);
      pb[0] = (unsigned short)p01;
      pb[PB_STRIDE] = (unsigned short)(p01 >> 16);
      pb[2 * PB_STRIDE] = (unsigned short)p23;
      pb[3 * PB_STRIDE] = (unsigned short)(p23 >> 16);
    }
  __syncthreads();  // pbuf + V0(db0) visible; red/red2 dead from here

  // ---- Phase 3: O = P V, double-buffered V^T: ONE barrier per chunk ----
  floatx4 oacc[2][2];
#pragma unroll
  for (int mt = 0; mt < 2; mt++)
#pragma unroll
    for (int nt = 0; nt < 2; nt++)
      oacc[mt][nt] = (floatx4){0.f, 0.f, 0.f, 0.f};

  // pv0: read db0 | write v1->db1 | issue v3
  VR v3 = v_load(kvb, tkg, 3, tid);
  SCHED_PIN();
  pv_chunk(pbuf, dbuf[0], 0, wave, quad, l16, oacc);
  v_write(dbuf[1], v1, tid);  // overwrites red/red2 tail: dead
  __syncthreads();

  // pv1: read db1 | write v2->db0
  pv_chunk(pbuf, dbuf[1], 1, wave, quad, l16, oacc);
  v_write(dbuf[0], v2, tid);
  __syncthreads();

  // pv2: read db0 | write v3->db1
  pv_chunk(pbuf, dbuf[0], 2, wave, quad, l16, oacc);
  v_write(dbuf[1], v3, tid);
  __syncthreads();

  // pv3: read db1
  pv_chunk(pbuf, dbuf[1], 3, wave, quad, l16, oacc);

  // ---- Phase 4: epilogue ----
  {
    float* op = out + (size_t)s * (NH * DH);
#pragma unroll
    for (int mt = 0; mt < 2; mt++)
#pragma unroll
      for (int nt = 0; nt < 2; nt++)
#pragma unroll
        for (int r4 = 0; r4 < 4; r4++) {
          int h = mt * 16 + quad * 4 + r4;
          int d = wave * 32 + nt * 16 + l16;
          op[h * DH + d] = oacc[mt][nt][r4] * inv[mt][r4];
        }
  }
}

extern "C" void kernel_launch(void* const* d_in, const int* in_sizes, int n_in,
                              void* d_out, int out_size, void* d_ws, size_t ws_size,
                              hipStream_t stream) {
  (void)in_sizes; (void)n_in; (void)out_size; (void)ws_size;
  const float* q    = (const float*)d_in[0];
  const float* kv   = (const float*)d_in[1];
  const float* sink = (const float*)d_in[2];
  const int*   topk = (const int*)d_in[3];
  float* out = (float*)d_out;
  unsigned short* kvb = (unsigned short*)d_ws;  // 2 MB bf16 KV

  kv_to_bf16<<<dim3(1024), dim3(256), 0, stream>>>(kv, kvb);
  sparse_attn_kernel<<<dim3(SQ), dim3(256), 0, stream>>>(q, kvb, sink, topk, out);
}